// Round 1
// baseline (369.949 us; speedup 1.0000x reference)
//
#include <hip/hip_runtime.h>

#define DHW 160
#define VOL (160*160*160)
#define PAD 5
#define KS 11
#define TS 32              // tile size (160 = 5*32, exact)
#define HT (TS + 2*PAD)    // 42 (tile + halo)

__device__ __forceinline__ void gauss_w(float w[KS]) {
    float s = 0.f;
#pragma unroll
    for (int i = 0; i < KS; ++i) {
        float d = (float)(i - PAD);
        w[i] = expf(-(d * d) / (2.f * 1.5f * 1.5f));
        s += w[i];
    }
    float inv = 1.f / s;
#pragma unroll
    for (int i = 0; i < KS; ++i) w[i] *= inv;
}

// 256-thread (4-wave) block reduction; result valid in thread 0.
__device__ __forceinline__ float block_reduce(float v, float* sm) {
#pragma unroll
    for (int off = 32; off > 0; off >>= 1)
        v += __shfl_down(v, off);
    int lane = threadIdx.x & 63;
    int wid  = threadIdx.x >> 6;
    if (lane == 0) sm[wid] = v;
    __syncthreads();
    float r = 0.f;
    if (threadIdx.x == 0) r = sm[0] + sm[1] + sm[2] + sm[3];
    return r;
}

// Kernel 1: for one z-slice tile, compute x-blur then y-blur of the 5 fields
// (p, t, p*p, t*t, p*t) with zero padding; write to buf[f][z][y][x].
// Also accumulates the L1 partial sum (each voxel counted exactly once).
__global__ __launch_bounds__(256) void k_xyblur(
    const float* __restrict__ pred, const float* __restrict__ targ,
    float* __restrict__ buf, double* __restrict__ accum, int batch)
{
    __shared__ float sP[HT][HT];
    __shared__ float sT[HT][HT];
    __shared__ float sF[5][HT][TS];
    __shared__ float sRed[4];

    float w[KS]; gauss_w(w);

    int tile = blockIdx.x;            // 0..24
    int z    = blockIdx.y;            // 0..159
    int x0 = (tile % 5) * TS;
    int y0 = (tile / 5) * TS;

    const float* p = pred + (size_t)batch * VOL + (size_t)z * DHW * DHW;
    const float* t = targ + (size_t)batch * VOL + (size_t)z * DHW * DHW;

    // Stage A: load (42x42) input tile with zero padding in x and y.
    for (int idx = threadIdx.x; idx < HT * HT; idx += 256) {
        int r = idx / HT, c = idx % HT;
        int gy = y0 + r - PAD, gx = x0 + c - PAD;
        float pv = 0.f, tv = 0.f;
        if (gy >= 0 && gy < DHW && gx >= 0 && gx < DHW) {
            pv = p[gy * DHW + gx];
            tv = t[gy * DHW + gx];
        }
        sP[r][c] = pv;
        sT[r][c] = tv;
    }
    __syncthreads();

    // Stage B: x-blur -> 5 fields, all 42 rows (y-halo kept), central 32 cols.
    for (int idx = threadIdx.x; idx < HT * TS; idx += 256) {
        int r = idx / TS, c = idx % TS;
        float bp = 0, bt = 0, bpp = 0, btt = 0, bpt = 0;
#pragma unroll
        for (int i = 0; i < KS; ++i) {
            float pv = sP[r][c + i], tv = sT[r][c + i];
            float wp = w[i] * pv, wt = w[i] * tv;
            bp  += wp;      bt  += wt;
            bpp += wp * pv; btt += wt * tv; bpt += wp * tv;
        }
        sF[0][r][c] = bp;  sF[1][r][c] = bt;
        sF[2][r][c] = bpp; sF[3][r][c] = btt; sF[4][r][c] = bpt;
    }
    __syncthreads();

    // Stage C: y-blur, write out; fused L1 partial.
    float l1 = 0.f;
    for (int idx = threadIdx.x; idx < TS * TS; idx += 256) {
        int yy = idx / TS, xx = idx % TS;
        float o0 = 0, o1 = 0, o2 = 0, o3 = 0, o4 = 0;
#pragma unroll
        for (int j = 0; j < KS; ++j) {
            float wj = w[j];
            o0 += wj * sF[0][yy + j][xx];
            o1 += wj * sF[1][yy + j][xx];
            o2 += wj * sF[2][yy + j][xx];
            o3 += wj * sF[3][yy + j][xx];
            o4 += wj * sF[4][yy + j][xx];
        }
        size_t base = (size_t)z * DHW * DHW + (size_t)(y0 + yy) * DHW + (x0 + xx);
        buf[0 * (size_t)VOL + base] = o0;
        buf[1 * (size_t)VOL + base] = o1;
        buf[2 * (size_t)VOL + base] = o2;
        buf[3 * (size_t)VOL + base] = o3;
        buf[4 * (size_t)VOL + base] = o4;
        l1 += fabsf(sP[yy + PAD][xx + PAD] - sT[yy + PAD][xx + PAD]);
    }
    float r = block_reduce(l1, sRed);
    if (threadIdx.x == 0) atomicAdd(&accum[0], (double)r);
}

// Kernel 2: z-blur of the 5 xy-blurred fields (zero padding in z),
// pointwise SSIM map, global sum.
__global__ __launch_bounds__(256) void k_zblur_ssim(
    const float* __restrict__ buf, double* __restrict__ accum)
{
    __shared__ float sG[5][HT][TS];
    __shared__ float sRed[4];

    float w[KS]; gauss_w(w);

    int tile = blockIdx.x;            // 0..24 : (zt, xt)
    int y    = blockIdx.y;            // 0..159
    int x0 = (tile % 5) * TS;
    int z0 = (tile / 5) * TS;

    for (int idx = threadIdx.x; idx < 5 * HT * TS; idx += 256) {
        int f   = idx / (HT * TS);
        int rem = idx % (HT * TS);
        int r = rem / TS, c = rem % TS;
        int gz = z0 + r - PAD;
        float v = 0.f;
        if (gz >= 0 && gz < DHW)
            v = buf[(size_t)f * VOL + (size_t)gz * DHW * DHW + (size_t)y * DHW + (x0 + c)];
        sG[f][r][c] = v;
    }
    __syncthreads();

    const float C1 = 0.01f * 0.01f;   // (K1*DATA_RANGE)^2
    const float C2 = 0.03f * 0.03f;   // (K2*DATA_RANGE)^2
    float ssum = 0.f;
    for (int idx = threadIdx.x; idx < TS * TS; idx += 256) {
        int zz = idx / TS, xx = idx % TS;
        float m1 = 0, m2 = 0, e11 = 0, e22 = 0, e12 = 0;
#pragma unroll
        for (int j = 0; j < KS; ++j) {
            float wj = w[j];
            m1  += wj * sG[0][zz + j][xx];
            m2  += wj * sG[1][zz + j][xx];
            e11 += wj * sG[2][zz + j][xx];
            e22 += wj * sG[3][zz + j][xx];
            e12 += wj * sG[4][zz + j][xx];
        }
        float mu11 = m1 * m1, mu22 = m2 * m2, mu12 = m1 * m2;
        float s1 = e11 - mu11, s2 = e22 - mu22, s12 = e12 - mu12;
        float num = (2.f * mu12 + C1) * (2.f * s12 + C2);
        float den = (mu11 + mu22 + C1) * (s1 + s2 + C2) + 1e-12f;
        ssum += num / den;
    }
    float r = block_reduce(ssum, sRed);
    if (threadIdx.x == 0) atomicAdd(&accum[1], (double)r);
}

__global__ void k_init(double* accum) {
    accum[0] = 0.0;
    accum[1] = 0.0;
}

__global__ void k_final(const double* __restrict__ accum, float* __restrict__ out) {
    const double n = 8192000.0;           // 2 * 160^3
    double l1   = accum[0] / n;
    double ssim = accum[1] / n;
    out[0] = (float)(0.7 * l1 + 0.3 * (1.0 - ssim));
}

extern "C" void kernel_launch(void* const* d_in, const int* in_sizes, int n_in,
                              void* d_out, int out_size, void* d_ws, size_t ws_size,
                              hipStream_t stream) {
    const float* pred = (const float*)d_in[0];
    const float* targ = (const float*)d_in[1];
    float* out = (float*)d_out;
    double* accum = (double*)d_ws;
    float* buf = (float*)((char*)d_ws + 256);   // 5 * VOL floats = 81.92 MB

    k_init<<<1, 1, 0, stream>>>(accum);
    dim3 grid(25, DHW);
    for (int b = 0; b < 2; ++b) {
        k_xyblur<<<grid, 256, 0, stream>>>(pred, targ, buf, accum, b);
        k_zblur_ssim<<<grid, 256, 0, stream>>>(buf, accum);
    }
    k_final<<<1, 1, 0, stream>>>(accum, out);
}

// Round 2
// 254.842 us; speedup vs baseline: 1.4517x; 1.4517x over previous
//
#include <hip/hip_runtime.h>

#define DHW 160
#define PLANE (160*160)
#define VOL (160*160*160)
#define PAD 5
#define KS 11
#define TX 16
#define TY 16
#define LZ 32              // z-chunk output length (5 chunks)
#define SR 26              // staged rows/cols = 16 + 2*PAD
#define SRP 28             // padded row (floats); 112 B, 16B-aligned rows
#define XBP 24             // sXB row stride (floats); 96 B aligned, 2-way banks (free)
#define NSLOT 6
#define STAGE_N (2*SR*SR)  // 1352

__device__ __forceinline__ void gauss_w(float w[KS]) {
    float s = 0.f;
#pragma unroll
    for (int i = 0; i < KS; ++i) {
        float d = (float)(i - PAD);
        w[i] = expf(-(d * d) / (2.f * 1.5f * 1.5f));
        s += w[i];
    }
    float inv = 1.f / s;
#pragma unroll
    for (int i = 0; i < KS; ++i) w[i] *= inv;
}

__device__ __forceinline__ float block_reduce(float v, float* sm) {
#pragma unroll
    for (int off = 32; off > 0; off >>= 1)
        v += __shfl_down(v, off);
    int lane = threadIdx.x & 63;
    int wid  = threadIdx.x >> 6;
    if (lane == 0) sm[wid] = v;
    __syncthreads();
    float r = 0.f;
    if (threadIdx.x == 0) r = sm[0] + sm[1] + sm[2] + sm[3];
    return r;
}

// Fused: stage slice -> x-blur (5 fields) -> y-blur -> per-thread register
// z-conv ring -> SSIM + L1, streaming along z. No intermediate global buffer.
__global__ __launch_bounds__(256, 2) void k_fused(
    const float* __restrict__ pred, const float* __restrict__ targ,
    double* __restrict__ accum)
{
    __shared__ __align__(16) float sIn[2][2][SR][SRP]; // [buf][p/t][row][col]
    __shared__ __align__(16) float sXB[5][SR][XBP];    // x-blurred fields
    __shared__ float sRed[4];

    float gw[KS]; gauss_w(gw);

    const int tile = blockIdx.x;           // 0..99
    const int xt = tile % 10, yt = tile / 10;
    const int z0 = blockIdx.y * LZ;        // 0..128
    const int b  = blockIdx.z;
    const float* __restrict__ P = pred + (size_t)b * VOL;
    const float* __restrict__ T = targ + (size_t)b * VOL;

    const int tid = threadIdx.x;
    const int tx = tid & 15, ty = tid >> 4;

    // ---- staging slot precompute (z-independent) ----
    const float* sptr[NSLOT];
    int  soff[NSLOT];
    bool sok[NSLOT];
#pragma unroll
    for (int i = 0; i < NSLOT; ++i) {
        int idx = tid + 256 * i;
        bool act = idx < STAGE_N;
        int idc = act ? idx : 0;
        int s   = idc / (SR * SR);
        int rem = idc - s * (SR * SR);
        int r   = rem / SR;
        int c   = rem - r * SR;
        int gy = yt * TY + r - PAD;
        int gx = xt * TX + c - PAD;
        bool inp = (gy >= 0 && gy < DHW && gx >= 0 && gx < DHW);
        sok[i]  = act && inp;
        soff[i] = (s * SR + r) * SRP + c;
        sptr[i] = (s ? T : P) + (inp ? (gy * DHW + gx) : 0);
    }

    auto stage_fetch = [&](int zz, float v[NSLOT]) {
        bool zok = (zz >= 0 && zz < DHW);
        size_t zo = (size_t)(zok ? zz : 0) * PLANE;
#pragma unroll
        for (int i = 0; i < NSLOT; ++i)
            v[i] = (zok && sok[i]) ? sptr[i][zo] : 0.f;
    };
    auto stage_write = [&](int buf, const float v[NSLOT]) {
        float* base = &sIn[buf][0][0][0];
#pragma unroll
        for (int i = 0; i < NSLOT; ++i)
            if (tid + 256 * i < STAGE_N) base[soff[i]] = v[i];
    };

    // per-thread z-conv pending ring (registers; static indices only)
    float pend[5][KS];
#pragma unroll
    for (int f = 0; f < 5; ++f)
#pragma unroll
        for (int j = 0; j < KS; ++j) pend[f][j] = 0.f;

    float l1s = 0.f, sss = 0.f;

    // prologue: stage first slice (z0-5) into buffer 0
    {
        float v[NSLOT];
        stage_fetch(z0 - PAD, v);
        stage_write(0, v);
    }
    __syncthreads();

    const int r4 = tid >> 2, cg = tid & 3;     // x-blur mapping: 26 rows x 4 col-groups
    const bool xbAct = (tid < SR * 4);         // 104 active threads

    const float C1 = 0.01f * 0.01f;
    const float C2 = 0.03f * 0.03f;

    for (int k = 0; k < LZ + 2 * PAD; ++k) {
        const int z = z0 - PAD + k;
        const int cur = k & 1, nxt = cur ^ 1;

        // (a) prefetch next slice into registers (consumed after barrier)
        float pf_v[NSLOT];
        stage_fetch(z + 1, pf_v);

        // (b) x-blur: 4 outputs/thread via aligned float4 LDS reads
        if (xbAct) {
            const float4* rp = (const float4*)&sIn[cur][0][r4][0];
            const float4* rt = (const float4*)&sIn[cur][1][r4][0];
            float4 a0 = rp[cg], a1 = rp[cg + 1], a2 = rp[cg + 2], a3 = rp[cg + 3];
            float4 b0 = rt[cg], b1 = rt[cg + 1], b2 = rt[cg + 2], b3 = rt[cg + 3];
            float pv[16] = {a0.x,a0.y,a0.z,a0.w, a1.x,a1.y,a1.z,a1.w,
                            a2.x,a2.y,a2.z,a2.w, a3.x,a3.y,a3.z,a3.w};
            float tv[16] = {b0.x,b0.y,b0.z,b0.w, b1.x,b1.y,b1.z,b1.w,
                            b2.x,b2.y,b2.z,b2.w, b3.x,b3.y,b3.z,b3.w};
            float pp[14], tt2[14], pt2[14];
#pragma unroll
            for (int i = 0; i < 14; ++i) {
                pp[i]  = pv[i] * pv[i];
                tt2[i] = tv[i] * tv[i];
                pt2[i] = pv[i] * tv[i];
            }
            float o[5][4];
#pragma unroll
            for (int oo = 0; oo < 4; ++oo) {
                float s0 = 0, s1 = 0, s2 = 0, s3 = 0, s4 = 0;
#pragma unroll
                for (int j = 0; j < KS; ++j) {
                    float w = gw[j];
                    s0 += w * pv[oo + j];
                    s1 += w * tv[oo + j];
                    s2 += w * pp[oo + j];
                    s3 += w * tt2[oo + j];
                    s4 += w * pt2[oo + j];
                }
                o[0][oo] = s0; o[1][oo] = s1; o[2][oo] = s2;
                o[3][oo] = s3; o[4][oo] = s4;
            }
#pragma unroll
            for (int f = 0; f < 5; ++f) {
                float4 w4 = make_float4(o[f][0], o[f][1], o[f][2], o[f][3]);
                ((float4*)&sXB[f][r4][0])[cg] = w4;
            }
        }

        // (c) fused L1 on the raw staged slice (each voxel counted once)
        if ((unsigned)(z - z0) < (unsigned)LZ) {
            float dp = sIn[cur][0][ty + PAD][tx + PAD];
            float dt = sIn[cur][1][ty + PAD][tx + PAD];
            l1s += fabsf(dp - dt);
        }

        __syncthreads();   // (d) sXB ready

        // (e) y-blur -> per-thread 5 field values for this slice
        float v0 = 0, v1 = 0, v2 = 0, v3 = 0, v4 = 0;
#pragma unroll
        for (int j = 0; j < KS; ++j) {
            float w = gw[j];
            v0 += w * sXB[0][ty + j][tx];
            v1 += w * sXB[1][ty + j][tx];
            v2 += w * sXB[2][ty + j][tx];
            v3 += w * sXB[3][ty + j][tx];
            v4 += w * sXB[4][ty + j][tx];
        }

        // (f) z-conv shift-accumulate (registers, static indices)
#pragma unroll
        for (int i = 0; i < KS - 1; ++i) {
            float w = gw[10 - i];
            pend[0][i] = pend[0][i + 1] + w * v0;
            pend[1][i] = pend[1][i + 1] + w * v1;
            pend[2][i] = pend[2][i + 1] + w * v2;
            pend[3][i] = pend[3][i + 1] + w * v3;
            pend[4][i] = pend[4][i + 1] + w * v4;
        }
        pend[0][10] = gw[0] * v0;
        pend[1][10] = gw[0] * v1;
        pend[2][10] = gw[0] * v2;
        pend[3][10] = gw[0] * v3;
        pend[4][10] = gw[0] * v4;

        // emit output z - PAD (now complete in pend[.][0])
        const int zo = z - PAD;
        if (zo >= z0 && zo < z0 + LZ) {
            float m1 = pend[0][0], m2 = pend[1][0];
            float e11 = pend[2][0], e22 = pend[3][0], e12 = pend[4][0];
            float mu11 = m1 * m1, mu22 = m2 * m2, mu12 = m1 * m2;
            float s1 = e11 - mu11, s2 = e22 - mu22, s12 = e12 - mu12;
            float num = (2.f * mu12 + C1) * (2.f * s12 + C2);
            float den = (mu11 + mu22 + C1) * (s1 + s2 + C2) + 1e-12f;
            sss += num / den;
        }

        // (g) commit prefetched slice to the other buffer
        stage_write(nxt, pf_v);

        __syncthreads();   // (h)
    }

    float r1 = block_reduce(l1s, sRed);
    __syncthreads();
    float r2 = block_reduce(sss, sRed);
    if (tid == 0) {
        atomicAdd(&accum[0], (double)r1);
        atomicAdd(&accum[1], (double)r2);
    }
}

__global__ void k_init(double* accum) {
    accum[0] = 0.0;
    accum[1] = 0.0;
}

__global__ void k_final(const double* __restrict__ accum, float* __restrict__ out) {
    const double n = 8192000.0;            // 2 * 160^3
    double l1   = accum[0] / n;
    double ssim = accum[1] / n;
    out[0] = (float)(0.7 * l1 + 0.3 * (1.0 - ssim));
}

extern "C" void kernel_launch(void* const* d_in, const int* in_sizes, int n_in,
                              void* d_out, int out_size, void* d_ws, size_t ws_size,
                              hipStream_t stream) {
    const float* pred = (const float*)d_in[0];
    const float* targ = (const float*)d_in[1];
    float* out = (float*)d_out;
    double* accum = (double*)d_ws;

    k_init<<<1, 1, 0, stream>>>(accum);
    dim3 grid(100, DHW / LZ, 2);           // tiles x z-chunks x batch = 1000 blocks
    k_fused<<<grid, 256, 0, stream>>>(pred, targ, accum);
    k_final<<<1, 1, 0, stream>>>(accum, out);
}

// Round 3
// 251.103 us; speedup vs baseline: 1.4733x; 1.0149x over previous
//
#include <hip/hip_runtime.h>

#define DHW 160
#define PLANE (160*160)
#define VOL (160*160*160)
#define PAD 5
#define KS 11
#define TX 16
#define TY 16
#define LZ 32              // z-chunk output length (5 chunks)
#define SR 26              // staged rows/cols = 16 + 2*PAD
#define SRP 40             // sIn row stride: banks (8*r4+4*cg)%32 -> uniform 2-way, b128 conflict-free
#define XBP 24             // sXB row stride: 2-way clean for b128 writes AND b32 y-blur reads
#define NSLOT 6
#define STAGE_N (2*SR*SR)  // 1352
#define NBLOCKS 1000

__device__ __forceinline__ void gauss_w(float w[KS]) {
    float s = 0.f;
#pragma unroll
    for (int i = 0; i < KS; ++i) {
        float d = (float)(i - PAD);
        w[i] = expf(-(d * d) / (2.f * 1.5f * 1.5f));
        s += w[i];
    }
    float inv = 1.f / s;
#pragma unroll
    for (int i = 0; i < KS; ++i) w[i] *= inv;
}

__device__ __forceinline__ float block_reduce(float v, float* sm) {
#pragma unroll
    for (int off = 32; off > 0; off >>= 1)
        v += __shfl_down(v, off);
    int lane = threadIdx.x & 63;
    int wid  = threadIdx.x >> 6;
    if (lane == 0) sm[wid] = v;
    __syncthreads();
    float r = 0.f;
    if (threadIdx.x == 0) r = sm[0] + sm[1] + sm[2] + sm[3];
    return r;
}

// Fully fused streaming kernel, 1 barrier per z-step:
//   iter k: x-blur slice S_k (sIn[k&1] -> sXB[k&1]), stage S_{k+1} -> sIn[(k+1)&1],
//           y-blur slice S_{k-1} from sXB[(k-1)&1], z-ring push, SSIM emit (lag 5).
__global__ __launch_bounds__(256, 3) void k_fused(
    const float* __restrict__ pred, const float* __restrict__ targ,
    double* __restrict__ accum, unsigned* __restrict__ cnt,
    float* __restrict__ out)
{
    __shared__ __align__(16) float sIn[2][2][SR][SRP]; // 16640 B
    __shared__ __align__(16) float sXB[2][5][SR][XBP]; // 24960 B
    __shared__ float sRed[4];

    float gw[KS]; gauss_w(gw);

    const int tile = blockIdx.x;           // 0..99
    const int xt = tile % 10, yt = tile / 10;
    const int z0 = blockIdx.y * LZ;        // 0..128
    const int b  = blockIdx.z;
    const float* __restrict__ P = pred + (size_t)b * VOL;
    const float* __restrict__ T = targ + (size_t)b * VOL;

    const int tid = threadIdx.x;
    const int tx = tid & 15, ty = tid >> 4;

    // ---- staging slot precompute (z-independent) ----
    const float* sptr[NSLOT];
    int  soff[NSLOT];
    bool sok[NSLOT];
#pragma unroll
    for (int i = 0; i < NSLOT; ++i) {
        int idx = tid + 256 * i;
        bool act = idx < STAGE_N;
        int idc = act ? idx : 0;
        int s   = idc / (SR * SR);
        int rem = idc - s * (SR * SR);
        int r   = rem / SR;
        int c   = rem - r * SR;
        int gy = yt * TY + r - PAD;
        int gx = xt * TX + c - PAD;
        bool inp = (gy >= 0 && gy < DHW && gx >= 0 && gx < DHW);
        sok[i]  = act && inp;
        soff[i] = (s * SR + r) * SRP + c;
        sptr[i] = (s ? T : P) + (inp ? (gy * DHW + gx) : 0);
    }

    auto stage_fetch = [&](int zz, float v[NSLOT]) {
        bool zok = (zz >= 0 && zz < DHW);
        size_t zo = (size_t)(zok ? zz : 0) * PLANE;
#pragma unroll
        for (int i = 0; i < NSLOT; ++i)
            v[i] = (zok && sok[i]) ? sptr[i][zo] : 0.f;
    };
    auto stage_write = [&](int buf, const float v[NSLOT]) {
        float* base = &sIn[buf][0][0][0];
#pragma unroll
        for (int i = 0; i < NSLOT; ++i)
            if (tid + 256 * i < STAGE_N) base[soff[i]] = v[i];
    };

    // per-thread z-conv pending ring (registers; static indices only)
    float pend[5][KS];
#pragma unroll
    for (int f = 0; f < 5; ++f)
#pragma unroll
        for (int j = 0; j < KS; ++j) pend[f][j] = 0.f;

    float l1s = 0.f, sss = 0.f;

    // prologue: stage slice S_0 = z0-5 into buffer 0
    {
        float v[NSLOT];
        stage_fetch(z0 - PAD, v);
        stage_write(0, v);
    }
    __syncthreads();

    const int r4 = tid >> 2, cg = tid & 3;     // x-blur: 26 rows x 4 col-groups
    const bool xbAct = (tid < SR * 4);         // 104 active threads

    const float C1 = 0.01f * 0.01f;
    const float C2 = 0.03f * 0.03f;

    // slices S_k = z0 - PAD + k, k = 0..41; iterations k = 0..42
    for (int k = 0; k <= LZ + 2 * PAD + 1; ++k) {
        const int cur = k & 1;

        // (a) issue prefetch of S_{k+1} early (consumed at (g))
        float pf_v[NSLOT];
        const bool doStage = (k <= LZ + 2 * PAD - 1);   // k <= 40
        if (doStage) stage_fetch(z0 - PAD + k + 1, pf_v);

        const bool haveSlice = (k <= LZ + 2 * PAD);     // k <= 41

        // (b) x-blur slice S_k: sIn[cur] -> sXB[cur]
        if (haveSlice && xbAct) {
            const float4* rp = (const float4*)&sIn[cur][0][r4][0];
            const float4* rt = (const float4*)&sIn[cur][1][r4][0];
            float4 a0 = rp[cg], a1 = rp[cg + 1], a2 = rp[cg + 2], a3 = rp[cg + 3];
            float4 b0 = rt[cg], b1 = rt[cg + 1], b2 = rt[cg + 2], b3 = rt[cg + 3];
            float pv[16] = {a0.x,a0.y,a0.z,a0.w, a1.x,a1.y,a1.z,a1.w,
                            a2.x,a2.y,a2.z,a2.w, a3.x,a3.y,a3.z,a3.w};
            float tv[16] = {b0.x,b0.y,b0.z,b0.w, b1.x,b1.y,b1.z,b1.w,
                            b2.x,b2.y,b2.z,b2.w, b3.x,b3.y,b3.z,b3.w};
            float pp[14], tt2[14], pt2[14];
#pragma unroll
            for (int i = 0; i < 14; ++i) {
                pp[i]  = pv[i] * pv[i];
                tt2[i] = tv[i] * tv[i];
                pt2[i] = pv[i] * tv[i];
            }
            float o[5][4];
#pragma unroll
            for (int oo = 0; oo < 4; ++oo) {
                float s0 = 0, s1 = 0, s2 = 0, s3 = 0, s4 = 0;
#pragma unroll
                for (int j = 0; j < KS; ++j) {
                    float w = gw[j];
                    s0 += w * pv[oo + j];
                    s1 += w * tv[oo + j];
                    s2 += w * pp[oo + j];
                    s3 += w * tt2[oo + j];
                    s4 += w * pt2[oo + j];
                }
                o[0][oo] = s0; o[1][oo] = s1; o[2][oo] = s2;
                o[3][oo] = s3; o[4][oo] = s4;
            }
#pragma unroll
            for (int f = 0; f < 5; ++f) {
                float4 w4 = make_float4(o[f][0], o[f][1], o[f][2], o[f][3]);
                ((float4*)&sXB[cur][f][r4][0])[cg] = w4;
            }
        }

        // (c) fused L1 on raw slice S_k (each voxel once; S_k in [z0, z0+LZ))
        if (haveSlice && (unsigned)(k - PAD) < (unsigned)LZ) {
            float dp = sIn[cur][0][ty + PAD][tx + PAD];
            float dt = sIn[cur][1][ty + PAD][tx + PAD];
            l1s += fabsf(dp - dt);
        }

        // (e) y-blur slice S_{k-1} from sXB[(k-1)&1] (written last iter), z-ring
        if (k >= 1) {
            const int pb = (k - 1) & 1;
            float v0 = 0, v1 = 0, v2 = 0, v3 = 0, v4 = 0;
#pragma unroll
            for (int j = 0; j < KS; ++j) {
                float w = gw[j];
                v0 += w * sXB[pb][0][ty + j][tx];
                v1 += w * sXB[pb][1][ty + j][tx];
                v2 += w * sXB[pb][2][ty + j][tx];
                v3 += w * sXB[pb][3][ty + j][tx];
                v4 += w * sXB[pb][4][ty + j][tx];
            }
#pragma unroll
            for (int i = 0; i < KS - 1; ++i) {
                float w = gw[10 - i];
                pend[0][i] = pend[0][i + 1] + w * v0;
                pend[1][i] = pend[1][i + 1] + w * v1;
                pend[2][i] = pend[2][i + 1] + w * v2;
                pend[3][i] = pend[3][i + 1] + w * v3;
                pend[4][i] = pend[4][i + 1] + w * v4;
            }
            pend[0][10] = gw[0] * v0;
            pend[1][10] = gw[0] * v1;
            pend[2][10] = gw[0] * v2;
            pend[3][10] = gw[0] * v3;
            pend[4][10] = gw[0] * v4;

            // emit z_out = S_{k-1} - PAD = z0 - 11 + k, valid for k in [11, 42]
            if (k >= 11) {
                float m1 = pend[0][0], m2 = pend[1][0];
                float e11 = pend[2][0], e22 = pend[3][0], e12 = pend[4][0];
                float mu11 = m1 * m1, mu22 = m2 * m2, mu12 = m1 * m2;
                float s1 = e11 - mu11, s2 = e22 - mu22, s12 = e12 - mu12;
                float num = (2.f * mu12 + C1) * (2.f * s12 + C2);
                float den = (mu11 + mu22 + C1) * (s1 + s2 + C2) + 1e-12f;
                sss += num / den;
            }
        }

        // (g) commit prefetched slice S_{k+1} to sIn[(k+1)&1]
        if (doStage) stage_write(cur ^ 1, pf_v);

        __syncthreads();   // single barrier per step
    }

    float r1 = block_reduce(l1s, sRed);
    __syncthreads();
    float r2 = block_reduce(sss, sRed);
    if (tid == 0) {
        atomicAdd(&accum[0], (double)r1);
        atomicAdd(&accum[1], (double)r2);
        __threadfence();
        unsigned prev = atomicAdd(cnt, 1u);
        if (prev == NBLOCKS - 1) {
            const double n = 8192000.0;   // 2 * 160^3
            double l1   = atomicAdd(&accum[0], 0.0) / n;
            double ssim = atomicAdd(&accum[1], 0.0) / n;
            out[0] = (float)(0.7 * l1 + 0.3 * (1.0 - ssim));
        }
    }
}

__global__ void k_init(double* accum, unsigned* cnt) {
    accum[0] = 0.0;
    accum[1] = 0.0;
    *cnt = 0u;
}

extern "C" void kernel_launch(void* const* d_in, const int* in_sizes, int n_in,
                              void* d_out, int out_size, void* d_ws, size_t ws_size,
                              hipStream_t stream) {
    const float* pred = (const float*)d_in[0];
    const float* targ = (const float*)d_in[1];
    float* out = (float*)d_out;
    double* accum = (double*)d_ws;
    unsigned* cnt = (unsigned*)((char*)d_ws + 64);

    k_init<<<1, 1, 0, stream>>>(accum, cnt);
    dim3 grid(100, DHW / LZ, 2);           // 1000 blocks
    k_fused<<<grid, 256, 0, stream>>>(pred, targ, accum, cnt, out);
}

// Round 4
// 226.039 us; speedup vs baseline: 1.6367x; 1.1109x over previous
//
#include <hip/hip_runtime.h>

#define DHW 160
#define PLANE (160*160)
#define VOL (160*160*160)
#define PAD 5
#define KS 11
#define TXW 16             // x tile width
#define TYH 32             // y tile height (2 outputs per thread)
#define LZ 32              // z-chunk output length (5 chunks)
#define SRX 26             // staged x extent = 16 + 2*PAD
#define SRY 42             // staged y extent = 32 + 2*PAD
#define SRP 44             // sIn row stride: b128 phase banks (12*r4+4cg)%32 -> 1 collision pair/phase
#define XBP 20             // sXB row stride: y-read banks (8*ty2+20j+tx)%32 -> exact 2-way (free)
#define NSLOT 9
#define STAGE_N (2*SRY*SRX)  // 2184
#define NBLOCKS 500

__device__ __forceinline__ void gauss_w(float w[KS]) {
    float s = 0.f;
#pragma unroll
    for (int i = 0; i < KS; ++i) {
        float d = (float)(i - PAD);
        w[i] = expf(-(d * d) / (2.f * 1.5f * 1.5f));
        s += w[i];
    }
    float inv = 1.f / s;
#pragma unroll
    for (int i = 0; i < KS; ++i) w[i] *= inv;
}

__device__ __forceinline__ float block_reduce(float v, float* sm) {
#pragma unroll
    for (int off = 32; off > 0; off >>= 1)
        v += __shfl_down(v, off);
    int lane = threadIdx.x & 63;
    int wid  = threadIdx.x >> 6;
    if (lane == 0) sm[wid] = v;
    __syncthreads();
    float r = 0.f;
    if (threadIdx.x == 0) r = sm[0] + sm[1] + sm[2] + sm[3];
    return r;
}

// Fused streaming kernel, 16x32 xy-tile, 2 y-outputs/thread, 1 barrier/z-step.
// iter k: x-blur S_k (sIn[k&1] -> sXB[k&1]), stage S_{k+1} -> sIn[(k+1)&1],
//         y-blur S_{k-1} from sXB[(k-1)&1] (2 outputs), z-ring push x2, emit (lag 5).
__global__ __launch_bounds__(256, 2) void k_fused(
    const float* __restrict__ pred, const float* __restrict__ targ,
    double* __restrict__ accum, unsigned* __restrict__ cnt,
    float* __restrict__ out)
{
    __shared__ __align__(16) float sIn[2][2][SRY][SRP]; // 29568 B
    __shared__ __align__(16) float sXB[2][5][SRY][XBP]; // 33600 B
    __shared__ float sRed[4];

    float gw[KS]; gauss_w(gw);

    const int tile = blockIdx.x;           // 0..49
    const int xt = tile % 10, yt = tile / 10;
    const int z0 = blockIdx.y * LZ;        // 0..128
    const int b  = blockIdx.z;
    const float* __restrict__ P = pred + (size_t)b * VOL;
    const float* __restrict__ T = targ + (size_t)b * VOL;

    const int tid = threadIdx.x;
    const int tx  = tid & 15;
    const int ty2 = tid >> 4;              // 0..15
    const int y0  = 2 * ty2;               // first of 2 output rows

    // ---- staging slot precompute (z-independent) ----
    const float* sptr[NSLOT];
    int  soff[NSLOT];
    bool sok[NSLOT];
#pragma unroll
    for (int i = 0; i < NSLOT; ++i) {
        int idx = tid + 256 * i;
        bool act = idx < STAGE_N;
        int idc = act ? idx : 0;
        int s   = idc / (SRY * SRX);
        int rem = idc - s * (SRY * SRX);
        int r   = rem / SRX;
        int c   = rem - r * SRX;
        int gy = yt * TYH + r - PAD;
        int gx = xt * TXW + c - PAD;
        bool inp = (gy >= 0 && gy < DHW && gx >= 0 && gx < DHW);
        sok[i]  = act && inp;
        soff[i] = (s * SRY + r) * SRP + c;
        sptr[i] = (s ? T : P) + (inp ? (gy * DHW + gx) : 0);
    }

    auto stage_fetch = [&](int zz, float v[NSLOT]) {
        bool zok = (zz >= 0 && zz < DHW);
        size_t zo = (size_t)(zok ? zz : 0) * PLANE;
#pragma unroll
        for (int i = 0; i < NSLOT; ++i)
            v[i] = (zok && sok[i]) ? sptr[i][zo] : 0.f;
    };
    auto stage_write = [&](int buf, const float v[NSLOT]) {
        float* base = &sIn[buf][0][0][0];
#pragma unroll
        for (int i = 0; i < NSLOT; ++i)
            if (tid + 256 * i < STAGE_N) base[soff[i]] = v[i];
    };

    // per-thread z-conv pending rings, one per output row (static indices only)
    float pend[2][5][KS];
#pragma unroll
    for (int o = 0; o < 2; ++o)
#pragma unroll
        for (int f = 0; f < 5; ++f)
#pragma unroll
            for (int j = 0; j < KS; ++j) pend[o][f][j] = 0.f;

    float l1s = 0.f, sss = 0.f;

    // prologue: stage slice S_0 = z0-5 into buffer 0
    {
        float v[NSLOT];
        stage_fetch(z0 - PAD, v);
        stage_write(0, v);
    }
    __syncthreads();

    const int r4 = tid >> 2, cg = tid & 3;     // x-blur: 42 rows x 4 col-groups
    const bool xbAct = (tid < SRY * 4);        // 168 active threads

    const float C1 = 0.01f * 0.01f;
    const float C2 = 0.03f * 0.03f;

    // slices S_k = z0 - PAD + k, k = 0..41; iterations k = 0..42
    for (int k = 0; k <= LZ + 2 * PAD + 1; ++k) {
        const int cur = k & 1;

        // (a) prefetch S_{k+1} (committed at (g))
        float pf_v[NSLOT];
        const bool doStage = (k <= LZ + 2 * PAD - 1);
        if (doStage) stage_fetch(z0 - PAD + k + 1, pf_v);

        const bool haveSlice = (k <= LZ + 2 * PAD);

        // (b) x-blur slice S_k: sIn[cur] -> sXB[cur]
        if (haveSlice && xbAct) {
            const float4* rp = (const float4*)&sIn[cur][0][r4][0];
            const float4* rt = (const float4*)&sIn[cur][1][r4][0];
            float4 a0 = rp[cg], a1 = rp[cg + 1], a2 = rp[cg + 2], a3 = rp[cg + 3];
            float4 b0 = rt[cg], b1 = rt[cg + 1], b2 = rt[cg + 2], b3 = rt[cg + 3];
            float pv[16] = {a0.x,a0.y,a0.z,a0.w, a1.x,a1.y,a1.z,a1.w,
                            a2.x,a2.y,a2.z,a2.w, a3.x,a3.y,a3.z,a3.w};
            float tv[16] = {b0.x,b0.y,b0.z,b0.w, b1.x,b1.y,b1.z,b1.w,
                            b2.x,b2.y,b2.z,b2.w, b3.x,b3.y,b3.z,b3.w};
            float pp[14], tt2[14], pt2[14];
#pragma unroll
            for (int i = 0; i < 14; ++i) {
                pp[i]  = pv[i] * pv[i];
                tt2[i] = tv[i] * tv[i];
                pt2[i] = pv[i] * tv[i];
            }
            float o[5][4];
#pragma unroll
            for (int oo = 0; oo < 4; ++oo) {
                float s0 = 0, s1 = 0, s2 = 0, s3 = 0, s4 = 0;
#pragma unroll
                for (int j = 0; j < KS; ++j) {
                    float w = gw[j];
                    s0 += w * pv[oo + j];
                    s1 += w * tv[oo + j];
                    s2 += w * pp[oo + j];
                    s3 += w * tt2[oo + j];
                    s4 += w * pt2[oo + j];
                }
                o[0][oo] = s0; o[1][oo] = s1; o[2][oo] = s2;
                o[3][oo] = s3; o[4][oo] = s4;
            }
#pragma unroll
            for (int f = 0; f < 5; ++f) {
                float4 w4 = make_float4(o[f][0], o[f][1], o[f][2], o[f][3]);
                ((float4*)&sXB[cur][f][r4][0])[cg] = w4;
            }
        }

        // (c) fused L1 on raw slice S_k (2 voxels/thread, each voxel once)
        if (haveSlice && (unsigned)(k - PAD) < (unsigned)LZ) {
            float dp0 = sIn[cur][0][y0 + PAD][tx + PAD];
            float dt0 = sIn[cur][1][y0 + PAD][tx + PAD];
            float dp1 = sIn[cur][0][y0 + 1 + PAD][tx + PAD];
            float dt1 = sIn[cur][1][y0 + 1 + PAD][tx + PAD];
            l1s += fabsf(dp0 - dt0) + fabsf(dp1 - dt1);
        }

        // (e) y-blur slice S_{k-1}: 12 taps serve 2 outputs; z-ring push x2
        if (k >= 1) {
            const int pb = (k - 1) & 1;
            float v[2][5];
#pragma unroll
            for (int f = 0; f < 5; ++f) {
                float tap[KS + 1];
#pragma unroll
                for (int j = 0; j < KS + 1; ++j)
                    tap[j] = sXB[pb][f][y0 + j][tx];
                float a0 = 0.f, a1 = 0.f;
#pragma unroll
                for (int j = 0; j < KS; ++j) {
                    float w = gw[j];
                    a0 += w * tap[j];
                    a1 += w * tap[j + 1];
                }
                v[0][f] = a0;
                v[1][f] = a1;
            }
#pragma unroll
            for (int o = 0; o < 2; ++o) {
#pragma unroll
                for (int i = 0; i < KS - 1; ++i) {
                    float w = gw[10 - i];
#pragma unroll
                    for (int f = 0; f < 5; ++f)
                        pend[o][f][i] = pend[o][f][i + 1] + w * v[o][f];
                }
#pragma unroll
                for (int f = 0; f < 5; ++f)
                    pend[o][f][10] = gw[0] * v[o][f];
            }

            // emit z_out = z0 - 11 + k, valid for k in [11, 42]
            if (k >= 11) {
#pragma unroll
                for (int o = 0; o < 2; ++o) {
                    float m1 = pend[o][0][0], m2 = pend[o][1][0];
                    float e11 = pend[o][2][0], e22 = pend[o][3][0], e12 = pend[o][4][0];
                    float mu11 = m1 * m1, mu22 = m2 * m2, mu12 = m1 * m2;
                    float s1 = e11 - mu11, s2 = e22 - mu22, s12 = e12 - mu12;
                    float num = (2.f * mu12 + C1) * (2.f * s12 + C2);
                    float den = (mu11 + mu22 + C1) * (s1 + s2 + C2) + 1e-12f;
                    sss += num / den;
                }
            }
        }

        // (g) commit prefetched slice S_{k+1} to sIn[(k+1)&1]
        if (doStage) stage_write(cur ^ 1, pf_v);

        __syncthreads();   // single barrier per step
    }

    float r1 = block_reduce(l1s, sRed);
    __syncthreads();
    float r2 = block_reduce(sss, sRed);
    if (tid == 0) {
        atomicAdd(&accum[0], (double)r1);
        atomicAdd(&accum[1], (double)r2);
        __threadfence();
        unsigned prev = atomicAdd(cnt, 1u);
        if (prev == NBLOCKS - 1) {
            const double n = 8192000.0;   // 2 * 160^3
            double l1   = atomicAdd(&accum[0], 0.0) / n;
            double ssim = atomicAdd(&accum[1], 0.0) / n;
            out[0] = (float)(0.7 * l1 + 0.3 * (1.0 - ssim));
        }
    }
}

__global__ void k_init(double* accum, unsigned* cnt) {
    accum[0] = 0.0;
    accum[1] = 0.0;
    *cnt = 0u;
}

extern "C" void kernel_launch(void* const* d_in, const int* in_sizes, int n_in,
                              void* d_out, int out_size, void* d_ws, size_t ws_size,
                              hipStream_t stream) {
    const float* pred = (const float*)d_in[0];
    const float* targ = (const float*)d_in[1];
    float* out = (float*)d_out;
    double* accum = (double*)d_ws;
    unsigned* cnt = (unsigned*)((char*)d_ws + 64);

    k_init<<<1, 1, 0, stream>>>(accum, cnt);
    dim3 grid(50, DHW / LZ, 2);            // 500 blocks
    k_fused<<<grid, 256, 0, stream>>>(pred, targ, accum, cnt, out);
}